// Round 2
// baseline (39.885 us; speedup 1.0000x reference)
//
#include <hip/hip_runtime.h>

#define BM  32
#define KC  64
#define LDC 132   // cst leading dim in floats (16B-aligned rows, conflict-free b128 col reads)

__global__ __launch_bounds__(256, 2)
void kmad_main(const float* __restrict__ x, const float* __restrict__ coords,
               int* __restrict__ out) {
    __shared__ float xs[BM][KC];        // 8 KB   [row][d]
    __shared__ float cst[KC][LDC];      // 33 KB  [d][col] (transposed coords chunk)
    __shared__ float nsqs[128];

    const int t  = threadIdx.x;
    const int ty = t >> 5;              // 0..7  -> row group
    const int tx = t & 31;              // 0..31 -> col group
    const int r0 = ty * 4;
    const int c0 = tx * 4;
    const int row0 = blockIdx.x * BM;

    float acc[4][4] = {};
    float nacc = 0.f;

    #pragma unroll 1
    for (int d0 = 0; d0 < 256; d0 += KC) {
        // ---- global loads to registers (overlap with previous compute) ----
        float4 xv[2];
        #pragma unroll
        for (int k = 0; k < 2; ++k) {
            int f = t + k * 256;
            int row = f >> 4, d4 = f & 15;
            xv[k] = *(const float4*)&x[(size_t)(row0 + row) * 256 + d0 + d4 * 4];
        }
        float4 cv[8];
        #pragma unroll
        for (int k = 0; k < 8; ++k) {
            int g = t + k * 256;            // g = d4*128 + c
            int c = g & 127, d4 = g >> 7;
            cv[k] = *(const float4*)&coords[(size_t)c * 256 + d0 + d4 * 4];
        }
        __syncthreads();   // previous chunk's compute done -> safe to overwrite LDS
        #pragma unroll
        for (int k = 0; k < 2; ++k) {
            int f = t + k * 256;
            int row = f >> 4, d4 = f & 15;
            *(float4*)&xs[row][d4 * 4] = xv[k];
        }
        #pragma unroll
        for (int k = 0; k < 8; ++k) {
            int g = t + k * 256;
            int c = g & 127, d4 = g >> 7;
            cst[d4 * 4 + 0][c] = cv[k].x;
            cst[d4 * 4 + 1][c] = cv[k].y;
            cst[d4 * 4 + 2][c] = cv[k].z;
            cst[d4 * 4 + 3][c] = cv[k].w;
        }
        __syncthreads();

        // ---- sqnorm accumulation from staged chunk (threads 0..127, col = t) ----
        if (t < 128) {
            #pragma unroll 8
            for (int dd = 0; dd < KC; ++dd) {
                float v = cst[dd][t];
                nacc = fmaf(v, v, nacc);
            }
        }

        // ---- GEMM micro-kernel: 4 rows x 4 cols, outer product over d ----
        #pragma unroll
        for (int dd = 0; dd < KC; dd += 4) {
            float4 a0 = *(const float4*)&xs[r0 + 0][dd];
            float4 a1 = *(const float4*)&xs[r0 + 1][dd];
            float4 a2 = *(const float4*)&xs[r0 + 2][dd];
            float4 a3 = *(const float4*)&xs[r0 + 3][dd];
            float4 b0 = *(const float4*)&cst[dd + 0][c0];
            float4 b1 = *(const float4*)&cst[dd + 1][c0];
            float4 b2 = *(const float4*)&cst[dd + 2][c0];
            float4 b3 = *(const float4*)&cst[dd + 3][c0];
#define FMA4(av, bv, i) \
            acc[i][0] = fmaf(av, bv.x, acc[i][0]); \
            acc[i][1] = fmaf(av, bv.y, acc[i][1]); \
            acc[i][2] = fmaf(av, bv.z, acc[i][2]); \
            acc[i][3] = fmaf(av, bv.w, acc[i][3]);
            FMA4(a0.x, b0, 0) FMA4(a0.y, b1, 0) FMA4(a0.z, b2, 0) FMA4(a0.w, b3, 0)
            FMA4(a1.x, b0, 1) FMA4(a1.y, b1, 1) FMA4(a1.z, b2, 1) FMA4(a1.w, b3, 1)
            FMA4(a2.x, b0, 2) FMA4(a2.y, b1, 2) FMA4(a2.z, b2, 2) FMA4(a2.w, b3, 2)
            FMA4(a3.x, b0, 3) FMA4(a3.y, b1, 3) FMA4(a3.z, b2, 3) FMA4(a3.w, b3, 3)
#undef FMA4
        }
    }

    // ---- epilogue: s = acc + nsq[col]; two-smallest per row; out = (m2 > s) ----
    if (t < 128) nsqs[t] = nacc;
    __syncthreads();
    const float nv0 = nsqs[c0 + 0];
    const float nv1 = nsqs[c0 + 1];
    const float nv2 = nsqs[c0 + 2];
    const float nv3 = nsqs[c0 + 3];

    #pragma unroll
    for (int i = 0; i < 4; ++i) {
        float s0 = acc[i][0] + nv0;
        float s1 = acc[i][1] + nv1;
        float s2 = acc[i][2] + nv2;
        float s3 = acc[i][3] + nv3;

        // per-thread two smallest of {s0..s3}
        float m1 = fminf(s0, s1);
        float m2 = fmaxf(s0, s1);
        { float hi = fmaxf(m1, s2); m1 = fminf(m1, s2); m2 = fminf(m2, hi); }
        { float hi = fmaxf(m1, s3); m1 = fminf(m1, s3); m2 = fminf(m2, hi); }

        // merge across the 32 lanes sharing this row (xor masks stay in the half-wave)
        #pragma unroll
        for (int m = 1; m <= 16; m <<= 1) {
            float o1 = __shfl_xor(m1, m);
            float o2 = __shfl_xor(m2, m);
            float hi = fmaxf(m1, o1);
            m1 = fminf(m1, o1);
            m2 = fminf(fminf(m2, o2), hi);
        }

        int4 o;
        o.x = (m2 > s0) ? 1 : 0;
        o.y = (m2 > s1) ? 1 : 0;
        o.z = (m2 > s2) ? 1 : 0;
        o.w = (m2 > s3) ? 1 : 0;
        *(int4*)&out[(size_t)(row0 + r0 + i) * 128 + c0] = o;
    }
}

extern "C" void kernel_launch(void* const* d_in, const int* in_sizes, int n_in,
                              void* d_out, int out_size, void* d_ws, size_t ws_size,
                              hipStream_t stream) {
    const float* x      = (const float*)d_in[0];   // (16384, 256) fp32
    const float* coords = (const float*)d_in[1];   // (128, 256)   fp32
    int* out = (int*)d_out;                        // (16384, 128) bool -> int32 0/1
    kmad_main<<<512, 256, 0, stream>>>(x, coords, out);
}